// Round 5
// baseline (1036.349 us; speedup 1.0000x reference)
//
#include <hip/hip_runtime.h>
#include <math.h>

#define NROWS 16384
#define NCOLS 16384
#define DIM   128
#define TM    256
#define TN    64
#define NSPLIT 8
#define CPS   (NCOLS/NSPLIT)   // 2048 cols per split
#define NCH   (CPS/TN)         // 32 chunks
#define KP    8

typedef __attribute__((ext_vector_type(8)))  short bf16x8;
typedef __attribute__((ext_vector_type(4)))  float f32x4;
typedef __attribute__((ext_vector_type(16))) float f32x16;
typedef __attribute__((ext_vector_type(4)))  unsigned int u32x4;

__device__ __forceinline__ unsigned short bf16_rne(float x) {
  unsigned u = __float_as_uint(x);
  unsigned r = u + 0x7fffu + ((u >> 16) & 1u);
  return (unsigned short)(r >> 16);
}

// ---- kernel 0: build per-chunk MFMA-fragment image of C (bf16 hi/lo) ----
// Image: 256 chunks x 32KB. Chunk: hi [0,16K) 16 tiles (cb*8+ks) of 1KB;
// tile slot byte = T*1024 + ((sub<<5)|(c&31))*16 + e*2; lo at +16K.
__global__ __launch_bounds__(256) void split_kernel(
    const float* __restrict__ C, unsigned char* __restrict__ Cimg)
{
  const unsigned u = blockIdx.x * 256 + threadIdx.x;  // 131072 threads
  const int c  = u & 16383;      // cluster id (S column)
  const int ks = u >> 14;        // k-slice of 16
  const f32x4* src = (const f32x4*)(C + (size_t)c * DIM + ks * 16);
  f32x4 f[4];
  f[0] = src[0]; f[1] = src[1]; f[2] = src[2]; f[3] = src[3];
  unsigned tb = (((unsigned)(c >> 6)) << 15)
              + ((unsigned)(((c >> 5) & 1) * 8 + ks) << 10)
              + ((unsigned)(c & 31) << 4);
  #pragma unroll
  for (int sub = 0; sub < 2; ++sub) {
    bf16x8 h, l;
    #pragma unroll
    for (int e = 0; e < 8; ++e) {
      float x = f[sub * 2 + (e >> 2)][e & 3];
      unsigned short hb = bf16_rne(x);
      float xh = __uint_as_float((unsigned)hb << 16);
      l[e] = (short)bf16_rne(x - xh);
      h[e] = (short)hb;
    }
    *(bf16x8*)&Cimg[tb + sub * 512]           = h;
    *(bf16x8*)&Cimg[tb + sub * 512 + 16384]   = l;
  }
}

// ---- kernel 1: fused GEMM (32x32x16 swapped-operand, 3-term bf16x2)
//      + direct S store + per-row top-8 candidates ----
__global__ __launch_bounds__(512, 4) void sim_topk_kernel(
    const float* __restrict__ Q, const unsigned char* __restrict__ Cimg,
    float* __restrict__ S, unsigned short* __restrict__ cand)
{
  __shared__ __align__(16) unsigned char lds[65536];   // 2 x 32KB chunk buffers
  const int t = threadIdx.x;
  const int w = t >> 6, lane = t & 63;

  const int bid = blockIdx.x;
  const int cs  = bid & 7;        // split == XCD (1MB image resident in its L2)
  const int rb  = bid >> 3;       // 0..63
  const int row0 = rb * TM;
  const int col0 = cs * CPS;

  // ---- A (query) fragments: wave w owns rows [row0+32w, +32); lane -> row lane&31 ----
  const int arow = row0 + w * 32 + (lane & 31);
  bf16x8 ah[8], al[8];
  {
    const f32x4* Qp = (const f32x4*)Q + (size_t)arow * 32 + ((lane >> 5) << 1);
    #pragma unroll
    for (int ks = 0; ks < 8; ++ks) {
      f32x4 x0 = Qp[ks * 4];
      f32x4 x1 = Qp[ks * 4 + 1];
      #pragma unroll
      for (int e = 0; e < 8; ++e) {
        float x = (e < 4) ? x0[e & 3] : x1[e & 3];
        unsigned short hb = bf16_rne(x);
        float xh = __uint_as_float((unsigned)hb << 16);
        al[ks][e] = (short)bf16_rne(x - xh);
        ah[ks][e] = (short)hb;
      }
    }
  }

  // ---- staging: thread t copies 4 x 16B at stride 8KB (linear chunk image) ----
  f32x4 st[4];
  auto gload = [&](int ch) {
    const f32x4* p = (const f32x4*)(Cimg + (((size_t)(cs * NCH + ch)) << 15)) + t;
    st[0] = p[0]; st[1] = p[512]; st[2] = p[1024]; st[3] = p[1536];
  };
  auto swrite = [&](unsigned buf) {
    #pragma unroll
    for (int r = 0; r < 4; ++r)
      *(f32x4*)&lds[buf + (unsigned)r * 8192u + (unsigned)t * 16u] = st[r];
  };

  gload(0); swrite(0u); gload(1);
  __syncthreads();

  float tv[KP]; int ti[KP];
  #pragma unroll
  for (int j = 0; j < KP; ++j) { tv[j] = -INFINITY; ti[j] = 0x7fffffff; }

  for (int ch = 0; ch < NCH; ++ch) {
    const unsigned cur = (ch & 1) ? 32768u : 0u;
    const int colg0 = col0 + ch * TN;

    if (ch + 1 < NCH) swrite(cur ^ 32768u);

    #pragma unroll
    for (int cb = 0; cb < 2; ++cb) {
      // MFMA: 3-term (hh, hl, lh); acc lane layout: col(lane&31)=S-row,
      // reg r -> S-col (r&3)+8*(r>>2)+4*(lane>>5) within 32-col block
      f32x16 acc = {0.f,0.f,0.f,0.f,0.f,0.f,0.f,0.f,0.f,0.f,0.f,0.f,0.f,0.f,0.f,0.f};
      #pragma unroll
      for (int ks = 0; ks < 8; ++ks) {
        unsigned o = cur + ((unsigned)(cb * 8 + ks) << 10) + ((unsigned)lane << 4);
        bf16x8 bh = *(const bf16x8*)&lds[o];
        bf16x8 bl = *(const bf16x8*)&lds[o + 16384u];
        acc = __builtin_amdgcn_mfma_f32_32x32x16_bf16(bh, ah[ks], acc, 0, 0, 0);
        acc = __builtin_amdgcn_mfma_f32_32x32x16_bf16(bl, ah[ks], acc, 0, 0, 0);
        acc = __builtin_amdgcn_mfma_f32_32x32x16_bf16(bh, al[ks], acc, 0, 0, 0);
      }

      // prefetch next-next chunk between the two halves (st dead during cb=0)
      if (cb == 0 && ch + 2 < NCH) gload(ch + 2);

      // direct stores + top-k on own row
      const int cb32 = colg0 + cb * 32 + ((lane >> 5) << 2);
      float* sp = &S[(size_t)arow * NCOLS + cb32];
      #pragma unroll
      for (int g = 0; g < 4; ++g) {
        f32x4 v = {acc[g * 4 + 0], acc[g * 4 + 1], acc[g * 4 + 2], acc[g * 4 + 3]};
        *(f32x4*)&sp[g * 8] = v;
        #pragma unroll
        for (int e = 0; e < 4; ++e) {
          float val = v[e];
          if (val > tv[KP - 1]) {     // strict >: ties keep earlier (lower) index
            tv[KP - 1] = val; ti[KP - 1] = cb32 + g * 8 + e;
            #pragma unroll
            for (int m = KP - 1; m > 0; --m) {
              if (tv[m] > tv[m - 1]) {
                float q = tv[m]; tv[m] = tv[m - 1]; tv[m - 1] = q;
                int   x = ti[m]; ti[m] = ti[m - 1]; ti[m - 1] = x;
              }
            }
          }
        }
      }
    }
    __syncthreads();  // cur reads done; next buffer staged (vmcnt/lgkm drained)
  }

  // ---- merge lane <-> lane+32 (two col-halves of same row) ----
  {
    float ov[KP]; int ox[KP];
    #pragma unroll
    for (int j = 0; j < KP; ++j) {
      ov[j] = __shfl_xor(tv[j], 32);
      ox[j] = __shfl_xor(ti[j], 32);
    }
    #pragma unroll
    for (int j = 0; j < KP; ++j) {
      if (ov[j] > tv[KP - 1] || (ov[j] == tv[KP - 1] && ox[j] < ti[KP - 1])) {
        tv[KP - 1] = ov[j]; ti[KP - 1] = ox[j];
        #pragma unroll
        for (int m = KP - 1; m > 0; --m) {
          if (tv[m] > tv[m - 1] || (tv[m] == tv[m - 1] && ti[m] < ti[m - 1])) {
            float q = tv[m]; tv[m] = tv[m - 1]; tv[m - 1] = q;
            int   x = ti[m]; ti[m] = ti[m - 1]; ti[m - 1] = x;
          }
        }
      }
    }
  }
  if (lane < 32) {
    // pack 8 ushort indices -> one 16B store at cand[arow][cs*8]
    u32x4 p;
    p.x = (unsigned)ti[0] | ((unsigned)ti[1] << 16);
    p.y = (unsigned)ti[2] | ((unsigned)ti[3] << 16);
    p.z = (unsigned)ti[4] | ((unsigned)ti[5] << 16);
    p.w = (unsigned)ti[6] | ((unsigned)ti[7] << 16);
    *(u32x4*)&cand[(size_t)arow * 64 + cs * 8] = p;
  }
}

// ---- kernel 2: exact fp64 re-rank of 64 candidates/row -> ids + top-8 sims ----
__global__ __launch_bounds__(256) void rerank_kernel(
    const float* __restrict__ Q, const float* __restrict__ C,
    const unsigned short* __restrict__ cand, float* __restrict__ out)
{
  const int t = threadIdx.x, w = t >> 6, lane = t & 63;
  const int r = blockIdx.x * 4 + w;
  const f32x4* Q4 = (const f32x4*)(Q + (size_t)r * DIM);

  const int cidx = cand[(size_t)r * 64 + lane];
  const f32x4* C4 = (const f32x4*)(C + (size_t)cidx * DIM);

  double acc = 0.0;
  #pragma unroll 8
  for (int d4 = 0; d4 < 32; ++d4) {
    f32x4 q = Q4[d4];
    f32x4 c = C4[d4];
    acc += (double)q[0] * (double)c[0];
    acc += (double)q[1] * (double)c[1];
    acc += (double)q[2] * (double)c[2];
    acc += (double)q[3] * (double)c[3];
  }

  double mv = acc;
  int    mi = cidx;

  float* oi = out;                           // ids as float32
  float* os = out + (size_t)NROWS * 8;       // top-8 sims

  for (int k = 0; k < 8; ++k) {
    double bv = mv; int bi = mi;
    #pragma unroll
    for (int off = 32; off >= 1; off >>= 1) {
      double ov = __shfl_xor(bv, off);
      int    o2 = __shfl_xor(bi, off);
      if (ov > bv || (ov == bv && o2 < bi)) { bv = ov; bi = o2; }
    }
    if (lane == 0) {
      os[(size_t)r * 8 + k] = (float)bv;
      oi[(size_t)r * 8 + k] = (bv >= 0.0) ? (float)bi : -1.0f;
    }
    if (mi == bi) mv = -1.0e300;   // candidate ids unique per row (disjoint splits)
  }
}

extern "C" void kernel_launch(void* const* d_in, const int* in_sizes, int n_in,
                              void* d_out, int out_size, void* d_ws, size_t ws_size,
                              hipStream_t stream) {
  const float* Q = (const float*)d_in[0];
  const float* C = (const float*)d_in[1];
  float* out = (float*)d_out;
  float* S   = out + (size_t)2 * NROWS * 8;                 // all_similarities

  unsigned char*  Cimg = (unsigned char*)d_ws;              // 8 MB fragment image
  unsigned short* cand = (unsigned short*)(Cimg + 8388608); // 2 MB: [16384][64]

  split_kernel<<<dim3(512), dim3(256), 0, stream>>>(C, Cimg);
  sim_topk_kernel<<<dim3((NROWS / TM) * NSPLIT), dim3(512), 0, stream>>>(Q, Cimg, S, cand);
  rerank_kernel<<<dim3(NROWS / 4), dim3(256), 0, stream>>>(Q, C, cand, out);
}

// Round 6
// 651.947 us; speedup vs baseline: 1.5896x; 1.5896x over previous
//
#include <hip/hip_runtime.h>
#include <math.h>

#define NROWS 16384
#define NCOLS 16384
#define DIM   128
#define TM    128
#define TN    64
#define NSPLIT 4
#define CPS   (NCOLS/NSPLIT)   // 4096 cols per split
#define NCH   (CPS/TN)         // 64 chunks
#define KP    8

typedef __attribute__((ext_vector_type(8))) short bf16x8;
typedef __attribute__((ext_vector_type(4))) float f32x4;

__device__ __forceinline__ unsigned short bf16_rne(float x) {
  unsigned u = __float_as_uint(x);
  unsigned r = u + 0x7fffu + ((u >> 16) & 1u);
  return (unsigned short)(r >> 16);
}

// Barrier that drains ONLY LDS ops; global stores/loads stay in flight.
#define BAR() do {                                   \
  __builtin_amdgcn_sched_barrier(0);                 \
  asm volatile("s_waitcnt lgkmcnt(0)" ::: "memory"); \
  __builtin_amdgcn_s_barrier();                      \
  __builtin_amdgcn_sched_barrier(0);                 \
} while (0)

// ---- kernel 0: build per-chunk MFMA fragment image of C (bf16 hi/lo) ----
// 256 chunks (64 cols each) x 32KB. Chunk: hi [0,16K): tile T=cbk*4+ks (1KB),
// slot = T*1024 + ln*16, ln = (col&15) | ((k>>3)&3)<<4, 8 k-elems per slot;
// lo at +16K.
__global__ __launch_bounds__(256) void split_kernel(
    const float* __restrict__ C, unsigned char* __restrict__ Cimg)
{
  const unsigned u = blockIdx.x * 256 + threadIdx.x;  // 131072 threads
  const int c  = u & 16383;      // cluster id (S column)
  const int kk = u >> 14;        // 0..7: k-group of 16
  const f32x4* src = (const f32x4*)(C + (size_t)c * DIM + kk * 16);
  f32x4 f[4];
  f[0] = src[0]; f[1] = src[1]; f[2] = src[2]; f[3] = src[3];
  const unsigned chunkbase = ((unsigned)(c >> 6)) << 15;
  const unsigned T = ((((unsigned)c >> 4) & 3u) << 2) | ((unsigned)kk >> 1);
  #pragma unroll
  for (int s = 0; s < 2; ++s) {
    bf16x8 h, l;
    #pragma unroll
    for (int e = 0; e < 8; ++e) {
      float x = f[s * 2 + (e >> 2)][e & 3];
      unsigned short hb = bf16_rne(x);
      float xh = __uint_as_float((unsigned)hb << 16);
      l[e] = (short)bf16_rne(x - xh);
      h[e] = (short)hb;
    }
    unsigned ln  = (unsigned)(c & 15) | ((((unsigned)kk * 2 + s) & 3u) << 4);
    unsigned off = chunkbase + (T << 10) + (ln << 4);
    *(bf16x8*)&Cimg[off]          = h;
    *(bf16x8*)&Cimg[off + 16384u] = l;
  }
}

// ---- kernel 1: fused GEMM (16x16x32 swapped-operand, 3-term bf16x2)
//      + direct S store + per-row top-8 candidates ----
__global__ __launch_bounds__(512, 4) void sim_topk_kernel(
    const float* __restrict__ Q, const unsigned char* __restrict__ Cimg,
    float* __restrict__ S, int* __restrict__ cand)
{
  __shared__ __align__(16) unsigned char lds[65536];   // 2 x 32KB chunk buffers
  const int t = threadIdx.x;
  const int w = t >> 6, lane = t & 63;

  // XCD-aware: 2 XCDs per col-split; split image (2MB) resident in L2 pair
  const int bid = blockIdx.x;
  const int xcd = bid & 7;
  const int cs  = xcd >> 1;                       // 0..3
  const int rb  = ((xcd & 1) << 6) | (bid >> 3);  // 0..127
  const int row0 = rb * TM;
  const int col0 = cs * CPS;

  // ---- A (query) fragments: wave w owns rows [row0+16w,+16); lane row = lane&15 ----
  const int arow = row0 + w * 16 + (lane & 15);
  bf16x8 ah[4], al[4];
  {
    const f32x4* Q4 = (const f32x4*)(Q + (size_t)arow * DIM);
    #pragma unroll
    for (int ks = 0; ks < 4; ++ks) {
      f32x4 x0 = Q4[ks * 8 + (lane >> 4) * 2];
      f32x4 x1 = Q4[ks * 8 + (lane >> 4) * 2 + 1];
      #pragma unroll
      for (int e = 0; e < 8; ++e) {
        float x = (e < 4) ? x0[e & 3] : x1[e & 3];
        unsigned short hb = bf16_rne(x);
        float xh = __uint_as_float((unsigned)hb << 16);
        al[ks][e] = (short)bf16_rne(x - xh);
        ah[ks][e] = (short)hb;
      }
    }
  }

  // ---- staging: pure linear copy of the 32KB chunk image ----
  f32x4 st[4];
  auto gload = [&](int ch) {
    const f32x4* p = (const f32x4*)(Cimg + (((size_t)(cs * NCH + ch)) << 15)) + t;
    st[0] = p[0]; st[1] = p[512]; st[2] = p[1024]; st[3] = p[1536];
  };
  auto swrite = [&](unsigned buf) {
    #pragma unroll
    for (int r = 0; r < 4; ++r)
      *(f32x4*)&lds[buf + (unsigned)r * 8192u + (unsigned)t * 16u] = st[r];
  };

  gload(0); swrite(0u); gload(1);
  BAR();   // buf0 staged

  float tv[KP]; int ti[KP];
  #pragma unroll
  for (int j = 0; j < KP; ++j) { tv[j] = -INFINITY; ti[j] = 0x7fffffff; }

  for (int ch = 0; ch < NCH; ++ch) {
    const unsigned cur = (ch & 1) ? 32768u : 0u;
    const int colg0 = col0 + ch * TN;

    // stage next chunk into other buffer (regs from previous gload)
    if (ch + 1 < NCH) swrite(cur ^ 32768u);

    // ---- MFMA: 3-term (hh, hl, lh), 4 independent acc chains ----
    f32x4 acc[4];
    #pragma unroll
    for (int c = 0; c < 4; ++c) acc[c] = {0.f, 0.f, 0.f, 0.f};
    #pragma unroll
    for (int ks = 0; ks < 4; ++ks) {
      #pragma unroll
      for (int cbk = 0; cbk < 4; ++cbk) {
        unsigned o = cur + ((unsigned)(cbk * 4 + ks) << 10) + ((unsigned)lane << 4);
        bf16x8 bh = *(const bf16x8*)&lds[o];
        bf16x8 bl = *(const bf16x8*)&lds[o + 16384u];
        acc[cbk] = __builtin_amdgcn_mfma_f32_16x16x32_bf16(bh, ah[ks], acc[cbk], 0, 0, 0);
        acc[cbk] = __builtin_amdgcn_mfma_f32_16x16x32_bf16(bl, ah[ks], acc[cbk], 0, 0, 0);
        acc[cbk] = __builtin_amdgcn_mfma_f32_16x16x32_bf16(bh, al[ks], acc[cbk], 0, 0, 0);
      }
    }

    // prefetch chunk+2 (st dead after swrite above)
    if (ch + 2 < NCH) gload(ch + 2);

    // ---- epilogue: direct f32x4 stores (64B/row per instr) + per-row top-k ----
    {
      const int cloc = (lane >> 4) * 4;
      float* sp = &S[(size_t)arow * NCOLS + colg0 + cloc];
      #pragma unroll
      for (int cbk = 0; cbk < 4; ++cbk) {
        *(f32x4*)&sp[cbk * 16] = acc[cbk];
        #pragma unroll
        for (int e = 0; e < 4; ++e) {
          float val = acc[cbk][e];
          if (val > tv[KP - 1]) {     // strict >: ties keep earlier (lower) index
            tv[KP - 1] = val; ti[KP - 1] = colg0 + cbk * 16 + cloc + e;
            #pragma unroll
            for (int m = KP - 1; m > 0; --m) {
              if (tv[m] > tv[m - 1]) {
                float q = tv[m]; tv[m] = tv[m - 1]; tv[m - 1] = q;
                int   x = ti[m]; ti[m] = ti[m - 1]; ti[m - 1] = x;
              }
            }
          }
        }
      }
    }
    BAR();   // LDS reads of cur done; nxt ds_writes visible. S-stores stay in flight.
  }

  // ---- merge the 4 col-group lanes of each row (lanes l, l^16, l^32, l^48) ----
  #pragma unroll
  for (int off = 16; off <= 32; off <<= 1) {
    float ov[KP]; int ox[KP];
    #pragma unroll
    for (int j = 0; j < KP; ++j) {
      ov[j] = __shfl_xor(tv[j], off);
      ox[j] = __shfl_xor(ti[j], off);
    }
    #pragma unroll
    for (int j = 0; j < KP; ++j) {
      if (ov[j] > tv[KP - 1] || (ov[j] == tv[KP - 1] && ox[j] < ti[KP - 1])) {
        tv[KP - 1] = ov[j]; ti[KP - 1] = ox[j];
        #pragma unroll
        for (int m = KP - 1; m > 0; --m) {
          if (tv[m] > tv[m - 1] || (tv[m] == tv[m - 1] && ti[m] < ti[m - 1])) {
            float q = tv[m]; tv[m] = tv[m - 1]; tv[m - 1] = q;
            int   x = ti[m]; ti[m] = ti[m - 1]; ti[m - 1] = x;
          }
        }
      }
    }
  }
  if (lane < 16) {
    int* dst = cand + ((size_t)arow * NSPLIT + cs) * KP;
    #pragma unroll
    for (int j = 0; j < KP; ++j) dst[j] = ti[j];
  }
}

// ---- kernel 2: exact fp64 re-rank of 32 candidates/row -> ids + top-8 sims ----
__global__ __launch_bounds__(256) void rerank_kernel(
    const float* __restrict__ Q, const float* __restrict__ C,
    const int* __restrict__ cand, float* __restrict__ out)
{
  const int t = threadIdx.x, w = t >> 6, lane = t & 63;
  const int r = blockIdx.x * 4 + w;
  const f32x4* Q4 = (const f32x4*)(Q + (size_t)r * DIM);

  int cidx = 0;
  if (lane < 32) cidx = cand[(size_t)r * 32 + lane];
  const f32x4* C4 = (const f32x4*)(C + (size_t)cidx * DIM);

  double acc = 0.0;
  #pragma unroll 8
  for (int d4 = 0; d4 < 32; ++d4) {
    f32x4 q = Q4[d4];
    f32x4 c = C4[d4];
    acc += (double)q[0] * (double)c[0];
    acc += (double)q[1] * (double)c[1];
    acc += (double)q[2] * (double)c[2];
    acc += (double)q[3] * (double)c[3];
  }

  double mv = (lane < 32) ? acc : -1.0e300;
  int    mi = (lane < 32) ? cidx : 0x7fffffff;

  float* oi = out;                           // ids as float32
  float* os = out + (size_t)NROWS * 8;       // top-8 sims

  for (int k = 0; k < 8; ++k) {
    double bv = mv; int bi = mi;
    #pragma unroll
    for (int off = 32; off >= 1; off >>= 1) {
      double ov = __shfl_xor(bv, off);
      int    o2 = __shfl_xor(bi, off);
      if (ov > bv || (ov == bv && o2 < bi)) { bv = ov; bi = o2; }
    }
    if (lane == 0) {
      os[(size_t)r * 8 + k] = (float)bv;
      oi[(size_t)r * 8 + k] = (bv >= 0.0) ? (float)bi : -1.0f;
    }
    if (mi == bi) mv = -1.0e300;   // candidate ids unique per row
  }
}

extern "C" void kernel_launch(void* const* d_in, const int* in_sizes, int n_in,
                              void* d_out, int out_size, void* d_ws, size_t ws_size,
                              hipStream_t stream) {
  const float* Q = (const float*)d_in[0];
  const float* C = (const float*)d_in[1];
  float* out = (float*)d_out;
  float* S   = out + (size_t)2 * NROWS * 8;              // all_similarities

  unsigned char* Cimg = (unsigned char*)d_ws;            // 8 MB fragment image
  int* cand = (int*)(Cimg + 8388608);                    // 2 MB: [16384][4][8]

  split_kernel<<<dim3(512), dim3(256), 0, stream>>>(C, Cimg);
  sim_topk_kernel<<<dim3((NROWS / TM) * NSPLIT), dim3(512), 0, stream>>>(Q, Cimg, S, cand);
  rerank_kernel<<<dim3(NROWS / 4), dim3(256), 0, stream>>>(Q, C, cand, out);
}

// Round 7
// 557.065 us; speedup vs baseline: 1.8604x; 1.1703x over previous
//
#include <hip/hip_runtime.h>
#include <math.h>

#define NROWS 16384
#define NCOLS 16384
#define DIM   128
#define TM    128
#define TN    64
#define NSPLIT 4
#define CPS   (NCOLS/NSPLIT)   // 4096 cols per split
#define NCH   (CPS/TN)         // 64 chunks
#define KP    8

typedef __attribute__((ext_vector_type(8))) short bf16x8;
typedef __attribute__((ext_vector_type(4))) float f32x4;

__device__ __forceinline__ unsigned short bf16_rne(float x) {
  unsigned u = __float_as_uint(x);
  unsigned r = u + 0x7fffu + ((u >> 16) & 1u);
  return (unsigned short)(r >> 16);
}

// Barrier that drains ONLY LDS ops; global stores/loads stay in flight.
#define BAR() do {                                   \
  __builtin_amdgcn_sched_barrier(0);                 \
  asm volatile("s_waitcnt lgkmcnt(0)" ::: "memory"); \
  __builtin_amdgcn_s_barrier();                      \
  __builtin_amdgcn_sched_barrier(0);                 \
} while (0)

// ---- kernel 0: build per-chunk MFMA fragment image of C (bf16 hi/lo) ----
// 256 chunks (64 cols each) x 32KB. Chunk: hi [0,16K): tile T=cbk*4+ks (1KB),
// slot = T*1024 + ln*16, ln = (col&15) | ((k>>3)&3)<<4, 8 k-elems per slot;
// lo at +16K.
__global__ __launch_bounds__(256) void split_kernel(
    const float* __restrict__ C, unsigned char* __restrict__ Cimg)
{
  const unsigned u = blockIdx.x * 256 + threadIdx.x;  // 131072 threads
  const int c  = u & 16383;      // cluster id (S column)
  const int kk = u >> 14;        // 0..7: k-group of 16
  const f32x4* src = (const f32x4*)(C + (size_t)c * DIM + kk * 16);
  f32x4 f[4];
  f[0] = src[0]; f[1] = src[1]; f[2] = src[2]; f[3] = src[3];
  const unsigned chunkbase = ((unsigned)(c >> 6)) << 15;
  const unsigned T = ((((unsigned)c >> 4) & 3u) << 2) | ((unsigned)kk >> 1);
  #pragma unroll
  for (int s = 0; s < 2; ++s) {
    bf16x8 h, l;
    #pragma unroll
    for (int e = 0; e < 8; ++e) {
      float x = f[s * 2 + (e >> 2)][e & 3];
      unsigned short hb = bf16_rne(x);
      float xh = __uint_as_float((unsigned)hb << 16);
      l[e] = (short)bf16_rne(x - xh);
      h[e] = (short)hb;
    }
    unsigned ln  = (unsigned)(c & 15) | ((((unsigned)kk * 2 + s) & 3u) << 4);
    unsigned off = chunkbase + (T << 10) + (ln << 4);
    *(bf16x8*)&Cimg[off]          = h;
    *(bf16x8*)&Cimg[off + 16384u] = l;
  }
}

// ---- kernel 1: fused GEMM (16x16x32 swapped-operand, 3-term bf16x2)
//      + direct S store + per-row top-8 candidates ----
// Blocks walk chunks in a per-block staggered cyclic order so concurrent
// blocks write DIFFERENT 256B column bands -> all HBM channels active.
__global__ __launch_bounds__(512, 4) void sim_topk_kernel(
    const float* __restrict__ Q, const unsigned char* __restrict__ Cimg,
    float* __restrict__ S, int* __restrict__ cand)
{
  __shared__ __align__(16) unsigned char lds[65536];   // 2 x 32KB chunk buffers
  const int t = threadIdx.x;
  const int w = t >> 6, lane = t & 63;

  // XCD-aware: 2 XCDs per col-split; split image (2MB) resident in L2 pair
  const int bid = blockIdx.x;
  const int xcd = bid & 7;
  const int cs  = xcd >> 1;                       // 0..3
  const int rb  = ((xcd & 1) << 6) | (bid >> 3);  // 0..127
  const int row0 = rb * TM;
  const int col0 = cs * CPS;
  const int phase = rb & (NCH - 1);               // chunk-order stagger

  // ---- A (query) fragments: wave w owns rows [row0+16w,+16); lane row = lane&15 ----
  const int arow = row0 + w * 16 + (lane & 15);
  bf16x8 ah[4], al[4];
  {
    const f32x4* Q4 = (const f32x4*)(Q + (size_t)arow * DIM);
    #pragma unroll
    for (int ks = 0; ks < 4; ++ks) {
      f32x4 x0 = Q4[ks * 8 + (lane >> 4) * 2];
      f32x4 x1 = Q4[ks * 8 + (lane >> 4) * 2 + 1];
      #pragma unroll
      for (int e = 0; e < 8; ++e) {
        float x = (e < 4) ? x0[e & 3] : x1[e & 3];
        unsigned short hb = bf16_rne(x);
        float xh = __uint_as_float((unsigned)hb << 16);
        al[ks][e] = (short)bf16_rne(x - xh);
        ah[ks][e] = (short)hb;
      }
    }
  }

  // ---- staging: pure linear copy of the 32KB chunk image ----
  f32x4 st[4];
  auto gload = [&](int ch) {
    const f32x4* p = (const f32x4*)(Cimg + (((size_t)(cs * NCH + ch)) << 15)) + t;
    st[0] = p[0]; st[1] = p[512]; st[2] = p[1024]; st[3] = p[1536];
  };
  auto swrite = [&](unsigned buf) {
    #pragma unroll
    for (int r = 0; r < 4; ++r)
      *(f32x4*)&lds[buf + (unsigned)r * 8192u + (unsigned)t * 16u] = st[r];
  };

  gload(phase); swrite(0u); gload((phase + 1) & (NCH - 1));
  BAR();   // buf0 staged

  float tv[KP]; int ti[KP];
  #pragma unroll
  for (int j = 0; j < KP; ++j) { tv[j] = -INFINITY; ti[j] = 0x7fffffff; }

  for (int i = 0; i < NCH; ++i) {
    const int ch = (phase + i) & (NCH - 1);
    const unsigned cur = (i & 1) ? 32768u : 0u;
    const int colg0 = col0 + ch * TN;

    // stage next chunk into other buffer; immediately refill st (max latency cover)
    if (i + 1 < NCH) swrite(cur ^ 32768u);
    if (i + 2 < NCH) gload((phase + i + 2) & (NCH - 1));

    // ---- MFMA: 3-term (hh, hl, lh), 4 independent acc chains ----
    f32x4 acc[4];
    #pragma unroll
    for (int c = 0; c < 4; ++c) acc[c] = {0.f, 0.f, 0.f, 0.f};
    #pragma unroll
    for (int ks = 0; ks < 4; ++ks) {
      #pragma unroll
      for (int cbk = 0; cbk < 4; ++cbk) {
        unsigned o = cur + ((unsigned)(cbk * 4 + ks) << 10) + ((unsigned)lane << 4);
        bf16x8 bh = *(const bf16x8*)&lds[o];
        bf16x8 bl = *(const bf16x8*)&lds[o + 16384u];
        acc[cbk] = __builtin_amdgcn_mfma_f32_16x16x32_bf16(bh, ah[ks], acc[cbk], 0, 0, 0);
        acc[cbk] = __builtin_amdgcn_mfma_f32_16x16x32_bf16(bl, ah[ks], acc[cbk], 0, 0, 0);
        acc[cbk] = __builtin_amdgcn_mfma_f32_16x16x32_bf16(bh, al[ks], acc[cbk], 0, 0, 0);
      }
    }

    // ---- epilogue: direct f32x4 stores (64B/row per instr) + per-row top-k ----
    {
      const int cloc = (lane >> 4) * 4;
      float* sp = &S[(size_t)arow * NCOLS + colg0 + cloc];
      #pragma unroll
      for (int cbk = 0; cbk < 4; ++cbk) {
        *(f32x4*)&sp[cbk * 16] = acc[cbk];
        #pragma unroll
        for (int e = 0; e < 4; ++e) {
          float val = acc[cbk][e];
          if (val > tv[KP - 1]) {     // strict >: ties keep earlier (lower) index
            tv[KP - 1] = val; ti[KP - 1] = colg0 + cbk * 16 + cloc + e;
            #pragma unroll
            for (int m = KP - 1; m > 0; --m) {
              if (tv[m] > tv[m - 1]) {
                float q = tv[m]; tv[m] = tv[m - 1]; tv[m - 1] = q;
                int   x = ti[m]; ti[m] = ti[m - 1]; ti[m - 1] = x;
              }
            }
          }
        }
      }
    }
    BAR();   // LDS reads of cur done; nxt ds_writes visible. S-stores stay in flight.
  }

  // ---- merge the 4 col-group lanes of each row (lanes l, l^16, l^32, l^48) ----
  #pragma unroll
  for (int off = 16; off <= 32; off <<= 1) {
    float ov[KP]; int ox[KP];
    #pragma unroll
    for (int j = 0; j < KP; ++j) {
      ov[j] = __shfl_xor(tv[j], off);
      ox[j] = __shfl_xor(ti[j], off);
    }
    #pragma unroll
    for (int j = 0; j < KP; ++j) {
      if (ov[j] > tv[KP - 1] || (ov[j] == tv[KP - 1] && ox[j] < ti[KP - 1])) {
        tv[KP - 1] = ov[j]; ti[KP - 1] = ox[j];
        #pragma unroll
        for (int m = KP - 1; m > 0; --m) {
          if (tv[m] > tv[m - 1] || (tv[m] == tv[m - 1] && ti[m] < ti[m - 1])) {
            float q = tv[m]; tv[m] = tv[m - 1]; tv[m - 1] = q;
            int   x = ti[m]; ti[m] = ti[m - 1]; ti[m - 1] = x;
          }
        }
      }
    }
  }
  if (lane < 16) {
    int* dst = cand + ((size_t)arow * NSPLIT + cs) * KP;
    #pragma unroll
    for (int j = 0; j < KP; ++j) dst[j] = ti[j];
  }
}

// ---- kernel 2: exact fp64 re-rank of 32 candidates/row -> ids + top-8 sims ----
__global__ __launch_bounds__(256) void rerank_kernel(
    const float* __restrict__ Q, const float* __restrict__ C,
    const int* __restrict__ cand, float* __restrict__ out)
{
  const int t = threadIdx.x, w = t >> 6, lane = t & 63;
  const int r = blockIdx.x * 4 + w;
  const f32x4* Q4 = (const f32x4*)(Q + (size_t)r * DIM);

  int cidx = 0;
  if (lane < 32) cidx = cand[(size_t)r * 32 + lane];
  const f32x4* C4 = (const f32x4*)(C + (size_t)cidx * DIM);

  double acc = 0.0;
  #pragma unroll 8
  for (int d4 = 0; d4 < 32; ++d4) {
    f32x4 q = Q4[d4];
    f32x4 c = C4[d4];
    acc += (double)q[0] * (double)c[0];
    acc += (double)q[1] * (double)c[1];
    acc += (double)q[2] * (double)c[2];
    acc += (double)q[3] * (double)c[3];
  }

  double mv = (lane < 32) ? acc : -1.0e300;
  int    mi = (lane < 32) ? cidx : 0x7fffffff;

  float* oi = out;                           // ids as float32
  float* os = out + (size_t)NROWS * 8;       // top-8 sims

  for (int k = 0; k < 8; ++k) {
    double bv = mv; int bi = mi;
    #pragma unroll
    for (int off = 32; off >= 1; off >>= 1) {
      double ov = __shfl_xor(bv, off);
      int    o2 = __shfl_xor(bi, off);
      if (ov > bv || (ov == bv && o2 < bi)) { bv = ov; bi = o2; }
    }
    if (lane == 0) {
      os[(size_t)r * 8 + k] = (float)bv;
      oi[(size_t)r * 8 + k] = (bv >= 0.0) ? (float)bi : -1.0f;
    }
    if (mi == bi) mv = -1.0e300;   // candidate ids unique per row
  }
}

extern "C" void kernel_launch(void* const* d_in, const int* in_sizes, int n_in,
                              void* d_out, int out_size, void* d_ws, size_t ws_size,
                              hipStream_t stream) {
  const float* Q = (const float*)d_in[0];
  const float* C = (const float*)d_in[1];
  float* out = (float*)d_out;
  float* S   = out + (size_t)2 * NROWS * 8;              // all_similarities

  unsigned char* Cimg = (unsigned char*)d_ws;            // 8 MB fragment image
  int* cand = (int*)(Cimg + 8388608);                    // 2 MB: [16384][4][8]

  split_kernel<<<dim3(512), dim3(256), 0, stream>>>(C, Cimg);
  sim_topk_kernel<<<dim3((NROWS / TM) * NSPLIT), dim3(512), 0, stream>>>(Q, Cimg, S, cand);
  rerank_kernel<<<dim3(NROWS / 4), dim3(256), 0, stream>>>(Q, C, cand, out);
}